// Round 15
// baseline (136.944 us; speedup 1.0000x reference)
//
#include <hip/hip_runtime.h>
#include <hip/hip_bf16.h>

typedef unsigned short ushort_t;
typedef _Float16 half_t;
typedef __attribute__((ext_vector_type(8))) _Float16 h8;     // 8 fp16 (4 VGPR frag)
typedef __attribute__((ext_vector_type(8))) short short8;
typedef __attribute__((ext_vector_type(4))) short short4_t;  // 8B store
typedef __attribute__((ext_vector_type(4))) float f32x4;
typedef __attribute__((ext_vector_type(16))) float f32x16;   // 32x32 MFMA C/D
typedef __attribute__((ext_vector_type(4))) float f4;

#define NB 4
#define SS 1024
#define HH 2048
#define NH 16
#define DD 128
#define MM (NB*SS)          // 4096 rows
#define NTOT 2304           // 2048 Q cols | 128 K | 128 V
#define COL_K 2048
#define COL_V 2176
#define KVB 32              // attention KV tile (32 KB LDS total -> 3 blocks/CU)
#define L2E 1.44269504089f

__device__ __forceinline__ ushort_t f2h(float x) {
    half_t h = (half_t)x;
    return *(ushort_t*)&h;
}
__device__ __forceinline__ f32x4 mfma16h(h8 a, h8 b, f32x4 c) {
    return __builtin_amdgcn_mfma_f32_16x16x32_f16(a, b, c, 0, 0, 0);
}
__device__ __forceinline__ f32x16 mfma32h(h8 a, h8 b, f32x16 c) {
    return __builtin_amdgcn_mfma_f32_32x32x16_f16(a, b, c, 0, 0, 0);
}
__device__ __forceinline__ void load_lds16(const ushort_t* g, ushort_t* l) {
    __builtin_amdgcn_global_load_lds(
        (const __attribute__((address_space(1))) unsigned int*)g,
        (__attribute__((address_space(3))) unsigned int*)l,
        16, 0, 0);
}

// ---------------- f32 -> fp16 convert (hidden states) ----------------
__global__ void k_cvt(const float* __restrict__ src, ushort_t* __restrict__ dst, int n) {
    int i = (blockIdx.x * blockDim.x + threadIdx.x) * 8;
    if (i + 7 < n) {
        f4 a = *(const f4*)(src + i);
        f4 b = *(const f4*)(src + i + 4);
        short8 o;
        #pragma unroll
        for (int j = 0; j < 4; ++j) { o[j] = (short)f2h(a[j]); o[4 + j] = (short)f2h(b[j]); }
        *(short8*)(dst + i) = o;
    }
}

// ---------------- tiled weight transpose+convert: W[n][H][Dd] -> T[n*Dd+d][HH] ----------------
__global__ __launch_bounds__(256) void k_tw(const float* __restrict__ W,
                                            ushort_t* __restrict__ T, int Dd) {
    __shared__ ushort_t t[64][74];
    const int n = blockIdx.z;
    const int h0 = blockIdx.x * 64, d0 = blockIdx.y * 64;
    const int r = threadIdx.x >> 2, cg = (threadIdx.x & 3) * 16;
    const float* src = W + ((size_t)n * HH + h0 + r) * Dd + d0 + cg;
    #pragma unroll
    for (int v = 0; v < 4; ++v) {
        f4 a = *(const f4*)(src + v * 4);
        #pragma unroll
        for (int j = 0; j < 4; ++j) t[r][cg + v * 4 + j] = f2h(a[j]);
    }
    __syncthreads();
    short8 o0, o1;
    #pragma unroll
    for (int j = 0; j < 8; ++j) { o0[j] = (short)t[cg + j][r]; o1[j] = (short)t[cg + 8 + j][r]; }
    ushort_t* dst = T + ((size_t)(n * Dd + d0 + r)) * HH + h0 + cg;
    *(short8*)dst = o0;
    *(short8*)(dst + 8) = o1;
}

// ---------------- fp16 GEMM (r11 exact — shape-adjusted ceiling for this problem) ------
__global__ __launch_bounds__(256) void k_gemm(
    const ushort_t* __restrict__ A, const ushort_t* __restrict__ B,
    const float* __restrict__ bq, const float* __restrict__ bk,
    const float* __restrict__ bvv, ushort_t* __restrict__ O,
    ushort_t* __restrict__ Vt) {

    constexpr int BK = 32;
    __shared__ ushort_t sA[128 * BK], sB[128 * BK];

    const int bid = blockIdx.x;
    const int swz = (bid & 7) * 72 + (bid >> 3);     // 576/8 = 72 per XCD, bijective
    const int m0 = (swz & 31) * 128;
    const int n0 = (swz >> 5) * 128;

    const int tid = threadIdx.x;
    const int w = tid >> 6, l = tid & 63;
    const int wr = w >> 1, wc = w & 1;
    f32x4 acc[4][4] = {};

    for (int kt = 0; kt < HH / BK; ++kt) {
        const int k0 = kt * BK;
        #pragma unroll
        for (int c = 0; c < 2; ++c) {
            int chunk = c * 4 + w;
            int idx = chunk * 512 + l * 8;
            int row = idx >> 5, kc = idx & 31;
            load_lds16(A + (size_t)(m0 + row) * HH + k0 + kc, &sA[chunk * 512]);
            load_lds16(B + (size_t)(n0 + row) * HH + k0 + kc, &sB[chunk * 512]);
        }
        __syncthreads();

        h8 a[4], b[4];
        #pragma unroll
        for (int i = 0; i < 4; ++i) {
            int ra = wr * 64 + i * 16 + (l & 15);
            int rb = wc * 64 + i * 16 + (l & 15);
            a[i] = *(const h8*)&sA[ra * 32 + (l >> 4) * 8];
            b[i] = *(const h8*)&sB[rb * 32 + (l >> 4) * 8];
        }
        #pragma unroll
        for (int i = 0; i < 4; ++i)
            #pragma unroll
            for (int j = 0; j < 4; ++j)
                acc[i][j] = mfma16h(a[i], b[j], acc[i][j]);
        __syncthreads();
    }

    #pragma unroll
    for (int i = 0; i < 4; ++i) {
        int row = m0 + wr * 64 + i * 16 + ((l >> 4) << 2);
        #pragma unroll
        for (int j = 0; j < 4; ++j) {
            int col = n0 + wc * 64 + j * 16 + (l & 15);
            float bv = (col < COL_K) ? bq[col]
                     : (col < COL_V) ? bk[col - COL_K]
                                     : bvv[col - COL_V];
            if (col < COL_V) {
                #pragma unroll
                for (int r = 0; r < 4; ++r)
                    O[(size_t)(row + r) * NTOT + col] = f2h(acc[i][j][r] + bv);
            } else {
                short4_t o;
                #pragma unroll
                for (int r = 0; r < 4; ++r) o[r] = (short)f2h(acc[i][j][r] + bv);
                *(short4_t*)&Vt[(size_t)(col - COL_V) * MM + row] = o;
            }
        }
    }
}

// ---------------- flash attention: 32x32x16, KVB=32, direct-O PV ----------------
// grid (S/128, N, B), 256 thr = 4 waves x 32 q. QK^T swapped (A=K, B=Q): lane (li,hi)
// holds S^T[t][q=li], t = (r&3)+8(r>>2)+4hi (m74/m101 layout). P-frag built with 2x
// v_permlane32_swap per 16-t chunk (verified r14, absmax-passing). PV uses the SWAPPED
// operand order acc = mfma(A=P-frag, B=V-frag): A/B lane-maps coincide, so the same regs
// serve; output is O[q=crow(r,hi)][d=dg*32+li] -> 32-lane x 4B = 128B-contiguous stores
// (r14's O^T had 32B segments -> 2.2x HBM write amplification). Per-q scalars (scl, inv)
// redistributed to crow layout via 16 __shfl (epilogue once; rescale is defer-max-rare).
__global__ __launch_bounds__(256, 3) void k_attn(
    const ushort_t* __restrict__ O, const ushort_t* __restrict__ Vt,
    float* __restrict__ Out) {

    __shared__ ushort_t sK[2][KVB * 128];     // [t][128], 4-bit mask swizzle, dbuf (16 KB)
    __shared__ ushort_t sVt[2][128 * KVB];    // [d][32], 2-bit chunk^(d&3) swizzle (16 KB)

    const int tid = threadIdx.x;
    const int w = tid >> 6, l = tid & 63;     // 4 waves
    const int li = l & 31, hi = l >> 5;
    const int q0 = blockIdx.x * 128;
    const int n = blockIdx.y, b = blockIdx.z;
    const int q = q0 + w * 32 + li;           // this lane's softmax-row

    const int mkK = (li & 3) | (((li >> 3) & 3) << 2);   // K-row swizzle mask (row=li)

    // Q: lane holds Q[q][c*16 + hi*8 .. +7] for c=0..7 (32x32 B-frag slices)
    h8 qv[8];
    {
        size_t base = ((size_t)(b * SS + q)) * NTOT + n * 128 + hi * 8;
        #pragma unroll
        for (int c = 0; c < 8; ++c)
            qv[c] = *(const h8*)&O[base + c * 16];
    }

    f32x16 acc0 = {}, acc1 = {}, acc2 = {}, acc3 = {};   // O[q=crow(r,hi)][dg*32+li]
    float m2 = -3.0e38f, lsum = 0.f;

    auto stage = [&](int bi, int t0) {
        // K tile 32x128 (8 KB = 8 segs, 2/wave); dest linear, source pre-swizzled
        #pragma unroll
        for (int c = 0; c < 2; ++c) {
            int seg = c * 4 + w;
            int oe = seg * 512 + l * 8;
            int row = oe >> 7;
            int mk = (row & 3) | (((row >> 3) & 3) << 2);
            int ce = (oe & 127) ^ (mk << 3);
            size_t g = (size_t)(b * SS + t0 + row) * NTOT + COL_K + ce;
            load_lds16(O + g, &sK[bi][seg * 512]);
        }
        // V^T tile 128x32 (8 KB); 16B-chunk swizzle: chunk ^= d&3
        #pragma unroll
        for (int c = 0; c < 2; ++c) {
            int seg = c * 4 + w;
            int oe = seg * 512 + l * 8;
            int d = oe >> 5;
            int ce = ((oe >> 3) & 3) ^ (d & 3);          // source chunk
            size_t g = (size_t)d * MM + b * SS + t0 + ce * 8;
            load_lds16(Vt + g, &sVt[bi][seg * 512]);
        }
    };

    stage(0, 0);
    constexpr int NT = SS / KVB;   // 32

    for (int it = 0; it < NT; ++it) {
        const int cur = it & 1;
        __syncthreads();
        if (it + 1 < NT) stage(cur ^ 1, (it + 1) * KVB);
        const ushort_t* sKc = sK[cur];
        const ushort_t* sVc = sVt[cur];

        // ---- QK^T: S^T[t][q=li], t = crow(r,hi) in 0..31
        f32x16 s0 = {};
        __builtin_amdgcn_s_setprio(1);
        #pragma unroll
        for (int c = 0; c < 8; ++c) {
            h8 kv = *(const h8*)&sKc[li * 128 + ((c * 16 + hi * 8) ^ (mkK << 3))];
            s0 = mfma32h(kv, qv[c], s0);
        }
        __builtin_amdgcn_s_setprio(0);

        // ---- online softmax for q=li (this lane 16 t, partner lane the other 16)
        float mv = s0[0];
        #pragma unroll
        for (int r = 1; r < 16; ++r) mv = fmaxf(mv, s0[r]);
        mv = fmaxf(mv, __shfl_xor(mv, 32));
        float pm2 = mv * L2E;

        if (!__all(pm2 <= m2 + 11.54f)) {    // defer-max, THR = 8 nats (wave-uniform)
            float mn = fmaxf(m2, pm2);
            float scl = exp2f(m2 - mn);
            lsum *= scl;
            // acc rows are q=crow(r,hi): fetch that q's scl from lane q
            #pragma unroll
            for (int r = 0; r < 16; ++r) {
                int qs = (r & 3) + 8 * (r >> 2) + 4 * hi;
                float sr = __shfl(scl, qs + (w << 6 >> 6) * 0 + (l & 64) * 0 + 0, 64);
                sr = __shfl(scl, qs);        // lane qs of this wave holds q=qs
                acc0[r] *= sr; acc1[r] *= sr; acc2[r] *= sr; acc3[r] *= sr;
            }
            m2 = mn;
        }

        // ---- exp + pack pairs: pk[j] = fp16(p[2j]) | fp16(p[2j+1])<<16  (reg idx j)
        unsigned int pk[8];
        #pragma unroll
        for (int j = 0; j < 8; ++j) {
            float pA = exp2f(fmaf(s0[2 * j],     L2E, -m2));
            float pB = exp2f(fmaf(s0[2 * j + 1], L2E, -m2));
            lsum += pA + pB;
            union { unsigned int u; half_t h[2]; } pu;
            pu.h[0] = (half_t)pA; pu.h[1] = (half_t)pB;
            pk[j] = pu.u;
        }

        // ---- PV: per 16-t chunk tc, P-frag via 2x permlane32_swap; A=P, B=V^T -> O direct
        __builtin_amdgcn_s_setprio(1);
        #pragma unroll
        for (int tc = 0; tc < 2; ++tc) {
            unsigned int a0 = pk[tc * 4 + 0], b0 = pk[tc * 4 + 2];
            unsigned int a1 = pk[tc * 4 + 1], b1 = pk[tc * 4 + 3];
            asm volatile("v_permlane32_swap_b32 %0, %1" : "+v"(a0), "+v"(b0));
            asm volatile("v_permlane32_swap_b32 %0, %1" : "+v"(a1), "+v"(b1));
            union { h8 h; unsigned int u[4]; } P2;
            P2.u[0] = a0; P2.u[1] = a1; P2.u[2] = b0; P2.u[3] = b1;

            const int ch = tc * 2 + hi;                  // t-chunk index (16B)
            #pragma unroll
            for (int dg = 0; dg < 4; ++dg) {
                int d = dg * 32 + li;
                h8 va = *(const h8*)&sVc[d * KVB + ((ch ^ (d & 3)) << 3)];
                f32x16& ac = (dg == 0) ? acc0 : (dg == 1) ? acc1 : (dg == 2) ? acc2 : acc3;
                ac = mfma32h(P2.h, va, ac);              // A=P-frag, B=V-frag -> O[q][d]
            }
        }
        __builtin_amdgcn_s_setprio(0);
    }

    // ---- epilogue: denominators, redistribute inv to crow layout, coalesced stores
    lsum += __shfl_xor(lsum, 32);
    float inv = 1.0f / lsum;
    float iv[16];
    #pragma unroll
    for (int r = 0; r < 16; ++r)
        iv[r] = __shfl(inv, (r & 3) + 8 * (r >> 2) + 4 * hi);

    #pragma unroll
    for (int r = 0; r < 16; ++r) {
        int qs = (r & 3) + 8 * (r >> 2) + 4 * hi;
        size_t base = (((size_t)b * NH + n) * SS + q0 + w * 32 + qs) * DD + li;
        Out[base +  0] = acc0[r] * iv[r];
        Out[base + 32] = acc1[r] * iv[r];
        Out[base + 64] = acc2[r] * iv[r];
        Out[base + 96] = acc3[r] * iv[r];
    }
}

// ---------------- workspace layout (bytes) ----------------
#define OFF_HC    ((size_t)0)                          // hidden fp16 [MM][HH]
#define OFF_BC    (OFF_HC + (size_t)MM*HH*2)           // Bcat fp16 [NTOT][HH]
#define OFF_O     (OFF_BC + (size_t)NTOT*HH*2)         // O fp16 [MM][NTOT]
#define OFF_VT    (OFF_O + (size_t)MM*NTOT*2)          // Vt fp16 [128][MM]

extern "C" void kernel_launch(void* const* d_in, const int* in_sizes, int n_in,
                              void* d_out, int out_size, void* d_ws, size_t ws_size,
                              hipStream_t stream) {
    const float* hs = (const float*)d_in[0];
    const float* Wq = (const float*)d_in[1];
    const float* bq = (const float*)d_in[2];
    const float* Wk = (const float*)d_in[3];
    const float* bk = (const float*)d_in[4];
    const float* Wv = (const float*)d_in[5];
    const float* bv = (const float*)d_in[6];
    float* out = (float*)d_out;
    char* ws = (char*)d_ws;

    ushort_t* hc   = (ushort_t*)(ws + OFF_HC);
    ushort_t* bcat = (ushort_t*)(ws + OFF_BC);
    ushort_t* Obuf = (ushort_t*)(ws + OFF_O);
    ushort_t* vt   = (ushort_t*)(ws + OFF_VT);

    // prep
    k_cvt<<<(MM*HH)/(256*8), 256, 0, stream>>>(hs, hc, MM*HH);
    dim3 gwq(HH/64, DD/64, NH);
    k_tw<<<gwq, 256, 0, stream>>>(Wq, bcat, DD);
    dim3 gwk(HH/64, DD/64, 1);
    k_tw<<<gwk, 256, 0, stream>>>(Wk, bcat + (size_t)COL_K*HH, DD);
    k_tw<<<gwk, 256, 0, stream>>>(Wv, bcat + (size_t)COL_V*HH, DD);

    // merged projection GEMM: 4096 x 2304 x 2048, bias fused, V^T written directly
    k_gemm<<<(MM/128)*(NTOT/128), 256, 0, stream>>>(hc, bcat, bq, bk, bv, Obuf, vt);

    // attention (32x32 MFMA, KVB=32, 4 waves x 32 q)
    dim3 ga(SS/128, NH, NB);
    k_attn<<<ga, 256, 0, stream>>>(Obuf, vt, out);
}

// Round 16
// 132.759 us; speedup vs baseline: 1.0315x; 1.0315x over previous
//
#include <hip/hip_runtime.h>
#include <hip/hip_bf16.h>

typedef unsigned short ushort_t;
typedef _Float16 half_t;
typedef __attribute__((ext_vector_type(8))) _Float16 h8;     // 8 fp16 (K=32 MFMA A/B frag)
typedef __attribute__((ext_vector_type(8))) short short8;
typedef __attribute__((ext_vector_type(4))) short short4_t;  // 8B store
typedef __attribute__((ext_vector_type(4))) float f32x4;
typedef __attribute__((ext_vector_type(4))) float f4;

#define NB 4
#define SS 1024
#define HH 2048
#define NH 16
#define DD 128
#define MM (NB*SS)          // 4096 rows
#define NTOT 2304           // 2048 Q cols | 128 K | 128 V
#define COL_K 2048
#define COL_V 2176
#define KVB 64
#define L2E 1.44269504089f

__device__ __forceinline__ ushort_t f2h(float x) {
    half_t h = (half_t)x;
    return *(ushort_t*)&h;
}
__device__ __forceinline__ f32x4 mfma16h(h8 a, h8 b, f32x4 c) {
    return __builtin_amdgcn_mfma_f32_16x16x32_f16(a, b, c, 0, 0, 0);
}
__device__ __forceinline__ void load_lds16(const ushort_t* g, ushort_t* l) {
    __builtin_amdgcn_global_load_lds(
        (const __attribute__((address_space(1))) unsigned int*)g,
        (__attribute__((address_space(3))) unsigned int*)l,
        16, 0, 0);
}

// ---------------- f32 -> fp16 convert (hidden states) ----------------
__global__ void k_cvt(const float* __restrict__ src, ushort_t* __restrict__ dst, int n) {
    int i = (blockIdx.x * blockDim.x + threadIdx.x) * 8;
    if (i + 7 < n) {
        f4 a = *(const f4*)(src + i);
        f4 b = *(const f4*)(src + i + 4);
        short8 o;
        #pragma unroll
        for (int j = 0; j < 4; ++j) { o[j] = (short)f2h(a[j]); o[4 + j] = (short)f2h(b[j]); }
        *(short8*)(dst + i) = o;
    }
}

// ---------------- tiled weight transpose+convert: W[n][H][Dd] -> T[n*Dd+d][HH] ----------------
__global__ __launch_bounds__(256) void k_tw(const float* __restrict__ W,
                                            ushort_t* __restrict__ T, int Dd) {
    __shared__ ushort_t t[64][74];
    const int n = blockIdx.z;
    const int h0 = blockIdx.x * 64, d0 = blockIdx.y * 64;
    const int r = threadIdx.x >> 2, cg = (threadIdx.x & 3) * 16;
    const float* src = W + ((size_t)n * HH + h0 + r) * Dd + d0 + cg;
    #pragma unroll
    for (int v = 0; v < 4; ++v) {
        f4 a = *(const f4*)(src + v * 4);
        #pragma unroll
        for (int j = 0; j < 4; ++j) t[r][cg + v * 4 + j] = f2h(a[j]);
    }
    __syncthreads();
    short8 o0, o1;
    #pragma unroll
    for (int j = 0; j < 8; ++j) { o0[j] = (short)t[cg + j][r]; o1[j] = (short)t[cg + 8 + j][r]; }
    ushort_t* dst = T + ((size_t)(n * Dd + d0 + r)) * HH + h0 + cg;
    *(short8*)dst = o0;
    *(short8*)(dst + 8) = o1;
}

// ---------------- fp16 GEMM: r11 structure, 8-wave blocks (TLP 9 -> 18 waves/CU) -------
// O[M][NTOT] = A[M][HH] * B[NTOT][HH]^T + bias (fused); V cols written transposed to Vt.
// Identical 128x128 tile, BK=32, single-buffer LDS, lockstep __syncthreads (preserves
// the sibling-block L2 B-column sharing that r12/r13's free-running schedules lost).
// 512 thr = 8 waves in a 4x2 grid of 32x64 sub-tiles; per wave: 2 A-frags, 4 B-frags,
// 8 MFMA/k-step; each wave stages one A-seg + one B-seg. Drain stalls at the barrier
// are now covered by 2x the co-resident waves.
__global__ __launch_bounds__(512, 4) void k_gemm(
    const ushort_t* __restrict__ A, const ushort_t* __restrict__ B,
    const float* __restrict__ bq, const float* __restrict__ bk,
    const float* __restrict__ bvv, ushort_t* __restrict__ O,
    ushort_t* __restrict__ Vt) {

    constexpr int BK = 32;
    __shared__ ushort_t sA[128 * BK], sB[128 * BK];

    const int bid = blockIdx.x;
    const int swz = (bid & 7) * 72 + (bid >> 3);     // 576/8 = 72 per XCD, bijective
    const int m0 = (swz & 31) * 128;
    const int n0 = (swz >> 5) * 128;

    const int tid = threadIdx.x;
    const int w = tid >> 6, l = tid & 63;            // 8 waves
    const int wr = w >> 1, wc = w & 1;               // 4x2 sub-tile grid (32 rows x 64 cols)
    f32x4 acc[2][4] = {};

    for (int kt = 0; kt < HH / BK; ++kt) {
        const int k0 = kt * BK;
        {
            int idx = w * 512 + l * 8;               // 8 segs per matrix, 1 per wave
            int row = idx >> 5, kc = idx & 31;
            load_lds16(A + (size_t)(m0 + row) * HH + k0 + kc, &sA[w * 512]);
            load_lds16(B + (size_t)(n0 + row) * HH + k0 + kc, &sB[w * 512]);
        }
        __syncthreads();

        h8 a[2], b[4];
        #pragma unroll
        for (int i = 0; i < 2; ++i) {
            int ra = wr * 32 + i * 16 + (l & 15);
            a[i] = *(const h8*)&sA[ra * 32 + (l >> 4) * 8];
        }
        #pragma unroll
        for (int j = 0; j < 4; ++j) {
            int rb = wc * 64 + j * 16 + (l & 15);
            b[j] = *(const h8*)&sB[rb * 32 + (l >> 4) * 8];
        }
        #pragma unroll
        for (int i = 0; i < 2; ++i)
            #pragma unroll
            for (int j = 0; j < 4; ++j)
                acc[i][j] = mfma16h(a[i], b[j], acc[i][j]);
        __syncthreads();
    }

    #pragma unroll
    for (int i = 0; i < 2; ++i) {
        int row = m0 + wr * 32 + i * 16 + ((l >> 4) << 2);
        #pragma unroll
        for (int j = 0; j < 4; ++j) {
            int col = n0 + wc * 64 + j * 16 + (l & 15);
            float bv = (col < COL_K) ? bq[col]
                     : (col < COL_V) ? bk[col - COL_K]
                                     : bvv[col - COL_V];
            if (col < COL_V) {
                #pragma unroll
                for (int r = 0; r < 4; ++r)
                    O[(size_t)(row + r) * NTOT + col] = f2h(acc[i][j][r] + bv);
            } else {
                short4_t o;
                #pragma unroll
                for (int r = 0; r < 4; ++r) o[r] = (short)f2h(acc[i][j][r] + bv);
                *(short4_t*)&Vt[(size_t)(col - COL_V) * MM + row] = o;
            }
        }
    }
}

// ---------------- flash attention (r11-exact): 8 waves x 16 q, permuted QK^T, K=32 PV --
// grid (S/128, N, B), 512 thr. K and V^T tiles via LDS (shared across 8 waves). K swizzle
// 4-bit (row&3)|(((row>>3)&3)<<2 -> 16 distinct slots per read (conflict-free). T5 setprio.
// This is the measured-best attn (~55 us); r14/r15 32x32 variants regressed (grid-capped
// TLP: 512 blocks = 2/CU; 256-thr blocks halve waves/CU).
__global__ __launch_bounds__(512, 4) void k_attn(
    const ushort_t* __restrict__ O, const ushort_t* __restrict__ Vt,
    float* __restrict__ Out) {

    __shared__ ushort_t sK[2][KVB * 128];     // [t][128], 4-bit mask swizzle, dbuf
    __shared__ ushort_t sVt[2][128 * KVB];    // [d][KVB], mask d&7, dbuf

    const int tid = threadIdx.x;
    const int w = tid >> 6, l = tid & 63;     // w in [0,8)
    const int lg = l >> 4, li = l & 15;
    const int q0 = blockIdx.x * 128;
    const int n = blockIdx.y, b = blockIdx.z;

    // Q fragments: rows q0 + w*16 + li
    h8 qv[4];
    {
        size_t base = ((size_t)(b * SS + q0 + w * 16 + li)) * NTOT + n * 128 + lg * 8;
        #pragma unroll
        for (int kk = 0; kk < 4; ++kk)
            qv[kk] = *(const h8*)&O[base + kk * 32];
    }

    f32x4 accO[8] = {};
    float m2 = -3.0e38f;
    float lsum = 0.f;

    auto stage = [&](int bi, int t0) {
        #pragma unroll
        for (int c = 0; c < 2; ++c) {
            int seg = c * 8 + w;                         // 16 segs over 8 waves
            int oe = seg * 512 + l * 8;
            int row = oe >> 7;
            int mk = (row & 3) | (((row >> 3) & 3) << 2);   // 4-bit: 16 distinct slots
            int ce = (oe & 127) ^ (mk << 3);
            size_t g = (size_t)(b * SS + t0 + row) * NTOT + COL_K + ce;
            load_lds16(O + g, &sK[bi][seg * 512]);
        }
        #pragma unroll
        for (int c = 0; c < 2; ++c) {
            int seg = c * 8 + w;
            int oe = seg * 512 + l * 8;
            int row = oe >> 6;
            int ce = (oe & 63) ^ ((row & 7) << 3);
            size_t g = (size_t)row * MM + b * SS + t0 + ce;
            load_lds16(Vt + g, &sVt[bi][seg * 512]);
        }
    };

    stage(0, 0);
    constexpr int NT = SS / KVB;   // 16

    for (int it = 0; it < NT; ++it) {
        const int cur = it & 1;
        const int t0 = it * KVB;
        __syncthreads();                       // drains stage(cur)
        if (it + 1 < NT) stage(cur ^ 1, t0 + KVB);
        const ushort_t* sKc = sK[cur];
        const ushort_t* sVc = sVt[cur];

        // ---- QK^T, permuted A-rows: reg r of s[ts] = S[t=(ts&1)*32+lg*8+(ts>>1)*4+r][q=li]
        f32x4 s[4] = {};
        __builtin_amdgcn_s_setprio(1);
        #pragma unroll
        for (int ts = 0; ts < 4; ++ts) {
            int trow = (ts & 1) * 32 + ((li >> 2) << 3) + ((ts >> 1) << 2) + (li & 3);
            int mk = (trow & 3) | (((trow >> 3) & 3) << 2);
            #pragma unroll
            for (int kk = 0; kk < 4; ++kk) {
                h8 kv = *(const h8*)&sKc[trow * 128 + ((kk * 32 + lg * 8) ^ (mk << 3))];
                s[ts] = mfma16h(kv, qv[kk], s[ts]);     // A=K, B=Q -> S^T
            }
        }
        __builtin_amdgcn_s_setprio(0);

        // ---- in-register online softmax (row q = li; 16 t-values per lane)
        float v = fmaxf(fmaxf(s[0][0], s[0][1]), fmaxf(s[0][2], s[0][3]));
        #pragma unroll
        for (int ts = 1; ts < 4; ++ts)
            v = fmaxf(v, fmaxf(fmaxf(s[ts][0], s[ts][1]), fmaxf(s[ts][2], s[ts][3])));
        v = fmaxf(v, __shfl_xor(v, 16));
        v = fmaxf(v, __shfl_xor(v, 32));
        float pm2 = v * L2E;

        if (!__all(pm2 <= m2 + 11.54f)) {   // defer-max, THR = 8 nats
            float mn = fmaxf(m2, pm2);
            float scl = exp2f(m2 - mn);
            lsum *= scl;
            #pragma unroll
            for (int db = 0; db < 8; ++db)
                #pragma unroll
                for (int r = 0; r < 4; ++r) accO[db][r] *= scl;
            m2 = mn;
        }

        h8 pb[2];
        #pragma unroll
        for (int ts = 0; ts < 4; ++ts)
            #pragma unroll
            for (int r = 0; r < 4; ++r) {
                float p = exp2f(fmaf(s[ts][r], L2E, -m2));
                lsum += p;
                pb[ts & 1][((ts >> 1) << 2) + r] = (half_t)p;
            }

        // ---- PV: K=32, b128 V^T reads from LDS (conflict-free 8-slot pattern)
        __builtin_amdgcn_s_setprio(1);
        #pragma unroll
        for (int db = 0; db < 8; ++db) {
            int d = db * 16 + li;
            const ushort_t* vbase = &sVc[d * KVB];
            int sw = (d & 7) << 3;
            #pragma unroll
            for (int ks = 0; ks < 2; ++ks) {
                h8 va = *(const h8*)&vbase[(ks * 32 + lg * 8) ^ sw];
                accO[db] = mfma16h(va, pb[ks], accO[db]);
            }
        }
        __builtin_amdgcn_s_setprio(0);
    }

    // ---- epilogue: finish denominator, normalize, write f32 [B][N][S][D]
    lsum += __shfl_xor(lsum, 16);
    lsum += __shfl_xor(lsum, 32);
    float inv = 1.0f / lsum;
    int q = q0 + w * 16 + li;
    size_t base = (((size_t)b * NH + n) * SS + q) * DD;
    #pragma unroll
    for (int db = 0; db < 8; ++db) {
        f4 o;
        #pragma unroll
        for (int r = 0; r < 4; ++r) o[r] = accO[db][r] * inv;
        *(f4*)&Out[base + db * 16 + lg * 4] = o;
    }
}

// ---------------- workspace layout (bytes) ----------------
#define OFF_HC    ((size_t)0)                          // hidden fp16 [MM][HH]
#define OFF_BC    (OFF_HC + (size_t)MM*HH*2)           // Bcat fp16 [NTOT][HH]
#define OFF_O     (OFF_BC + (size_t)NTOT*HH*2)         // O fp16 [MM][NTOT]
#define OFF_VT    (OFF_O + (size_t)MM*NTOT*2)          // Vt fp16 [128][MM]

extern "C" void kernel_launch(void* const* d_in, const int* in_sizes, int n_in,
                              void* d_out, int out_size, void* d_ws, size_t ws_size,
                              hipStream_t stream) {
    const float* hs = (const float*)d_in[0];
    const float* Wq = (const float*)d_in[1];
    const float* bq = (const float*)d_in[2];
    const float* Wk = (const float*)d_in[3];
    const float* bk = (const float*)d_in[4];
    const float* Wv = (const float*)d_in[5];
    const float* bv = (const float*)d_in[6];
    float* out = (float*)d_out;
    char* ws = (char*)d_ws;

    ushort_t* hc   = (ushort_t*)(ws + OFF_HC);
    ushort_t* bcat = (ushort_t*)(ws + OFF_BC);
    ushort_t* Obuf = (ushort_t*)(ws + OFF_O);
    ushort_t* vt   = (ushort_t*)(ws + OFF_VT);

    // prep
    k_cvt<<<(MM*HH)/(256*8), 256, 0, stream>>>(hs, hc, MM*HH);
    dim3 gwq(HH/64, DD/64, NH);
    k_tw<<<gwq, 256, 0, stream>>>(Wq, bcat, DD);
    dim3 gwk(HH/64, DD/64, 1);
    k_tw<<<gwk, 256, 0, stream>>>(Wk, bcat + (size_t)COL_K*HH, DD);
    k_tw<<<gwk, 256, 0, stream>>>(Wv, bcat + (size_t)COL_V*HH, DD);

    // merged projection GEMM: 4096 x 2304 x 2048, bias fused, V^T written directly
    k_gemm<<<(MM/128)*(NTOT/128), 512, 0, stream>>>(hc, bcat, bq, bk, bv, Obuf, vt);

    // attention (r11-exact)
    dim3 ga(SS/128, NH, NB);
    k_attn<<<ga, 512, 0, stream>>>(Obuf, vt, out);
}

// Round 17
// 124.899 us; speedup vs baseline: 1.0964x; 1.0629x over previous
//
#include <hip/hip_runtime.h>
#include <hip/hip_bf16.h>

typedef unsigned short ushort_t;
typedef _Float16 half_t;
typedef __attribute__((ext_vector_type(8))) _Float16 h8;     // 8 fp16 (K=32 MFMA A/B frag)
typedef __attribute__((ext_vector_type(8))) short short8;
typedef __attribute__((ext_vector_type(4))) short short4_t;  // 8B store
typedef __attribute__((ext_vector_type(4))) float f32x4;
typedef __attribute__((ext_vector_type(4))) float f4;

#define NB 4
#define SS 1024
#define HH 2048
#define NH 16
#define DD 128
#define MM (NB*SS)          // 4096 rows
#define NTOT 2304           // 2048 Q cols | 128 K | 128 V
#define COL_K 2048
#define COL_V 2176
#define KVB 64
#define L2E 1.44269504089f

__device__ __forceinline__ ushort_t f2h(float x) {
    half_t h = (half_t)x;
    return *(ushort_t*)&h;
}
__device__ __forceinline__ f32x4 mfma16h(h8 a, h8 b, f32x4 c) {
    return __builtin_amdgcn_mfma_f32_16x16x32_f16(a, b, c, 0, 0, 0);
}
__device__ __forceinline__ void load_lds16(const ushort_t* g, ushort_t* l) {
    __builtin_amdgcn_global_load_lds(
        (const __attribute__((address_space(1))) unsigned int*)g,
        (__attribute__((address_space(3))) unsigned int*)l,
        16, 0, 0);
}

// ---------------- f32 -> fp16 convert (hidden states) ----------------
__global__ void k_cvt(const float* __restrict__ src, ushort_t* __restrict__ dst, int n) {
    int i = (blockIdx.x * blockDim.x + threadIdx.x) * 8;
    if (i + 7 < n) {
        f4 a = *(const f4*)(src + i);
        f4 b = *(const f4*)(src + i + 4);
        short8 o;
        #pragma unroll
        for (int j = 0; j < 4; ++j) { o[j] = (short)f2h(a[j]); o[4 + j] = (short)f2h(b[j]); }
        *(short8*)(dst + i) = o;
    }
}

// ---------------- tiled weight transpose+convert: W[n][H][Dd] -> T[n*Dd+d][HH] ----------------
__global__ __launch_bounds__(256) void k_tw(const float* __restrict__ W,
                                            ushort_t* __restrict__ T, int Dd) {
    __shared__ ushort_t t[64][74];
    const int n = blockIdx.z;
    const int h0 = blockIdx.x * 64, d0 = blockIdx.y * 64;
    const int r = threadIdx.x >> 2, cg = (threadIdx.x & 3) * 16;
    const float* src = W + ((size_t)n * HH + h0 + r) * Dd + d0 + cg;
    #pragma unroll
    for (int v = 0; v < 4; ++v) {
        f4 a = *(const f4*)(src + v * 4);
        #pragma unroll
        for (int j = 0; j < 4; ++j) t[r][cg + v * 4 + j] = f2h(a[j]);
    }
    __syncthreads();
    short8 o0, o1;
    #pragma unroll
    for (int j = 0; j < 8; ++j) { o0[j] = (short)t[cg + j][r]; o1[j] = (short)t[cg + 8 + j][r]; }
    ushort_t* dst = T + ((size_t)(n * Dd + d0 + r)) * HH + h0 + cg;
    *(short8*)dst = o0;
    *(short8*)(dst + 8) = o1;
}

// ---------------- fp16 GEMM (r11 structure + LDS swizzle — the only delta) ------------
// O[M][NTOT] = A[M][HH] * B[NTOT][HH]^T + bias (fused); V cols written transposed to Vt.
// 4 waves, 128x128 tile, BK=32, single-buffer LDS, lockstep __syncthreads (r12/r13/r16
// showed pipeline/3-buf/8-wave variants all regress). NEW: 16B-chunk XOR swizzle
// chunk ^= (row>>1)&3 on BOTH the global_load_lds source and the fragment reads
// (rule #21 both-sides; r12 measured this staging/read pattern's conflicts -> 0).
__global__ __launch_bounds__(256) void k_gemm(
    const ushort_t* __restrict__ A, const ushort_t* __restrict__ B,
    const float* __restrict__ bq, const float* __restrict__ bk,
    const float* __restrict__ bvv, ushort_t* __restrict__ O,
    ushort_t* __restrict__ Vt) {

    constexpr int BK = 32;
    __shared__ ushort_t sA[128 * BK], sB[128 * BK];

    const int bid = blockIdx.x;
    const int swz = (bid & 7) * 72 + (bid >> 3);     // 576/8 = 72 per XCD, bijective
    const int m0 = (swz & 31) * 128;
    const int n0 = (swz >> 5) * 128;

    const int tid = threadIdx.x;
    const int w = tid >> 6, l = tid & 63;
    const int wr = w >> 1, wc = w & 1;
    f32x4 acc[4][4] = {};

    for (int kt = 0; kt < HH / BK; ++kt) {
        const int k0 = kt * BK;
        #pragma unroll
        for (int c = 0; c < 2; ++c) {
            int chunk = c * 4 + w;
            int idx = chunk * 512 + l * 8;
            int row = idx >> 5;
            int kc = (idx & 31) ^ (((row >> 1) & 3) << 3);   // pre-swizzled source
            load_lds16(A + (size_t)(m0 + row) * HH + k0 + kc, &sA[chunk * 512]);
            load_lds16(B + (size_t)(n0 + row) * HH + k0 + kc, &sB[chunk * 512]);
        }
        __syncthreads();

        h8 a[4], b[4];
        #pragma unroll
        for (int i = 0; i < 4; ++i) {
            int ra = wr * 64 + i * 16 + (l & 15);
            int rb = wc * 64 + i * 16 + (l & 15);
            a[i] = *(const h8*)&sA[ra * 32 + (((l >> 4) ^ ((ra >> 1) & 3)) << 3)];
            b[i] = *(const h8*)&sB[rb * 32 + (((l >> 4) ^ ((rb >> 1) & 3)) << 3)];
        }
        #pragma unroll
        for (int i = 0; i < 4; ++i)
            #pragma unroll
            for (int j = 0; j < 4; ++j)
                acc[i][j] = mfma16h(a[i], b[j], acc[i][j]);
        __syncthreads();
    }

    #pragma unroll
    for (int i = 0; i < 4; ++i) {
        int row = m0 + wr * 64 + i * 16 + ((l >> 4) << 2);
        #pragma unroll
        for (int j = 0; j < 4; ++j) {
            int col = n0 + wc * 64 + j * 16 + (l & 15);
            float bv = (col < COL_K) ? bq[col]
                     : (col < COL_V) ? bk[col - COL_K]
                                     : bvv[col - COL_V];
            if (col < COL_V) {
                #pragma unroll
                for (int r = 0; r < 4; ++r)
                    O[(size_t)(row + r) * NTOT + col] = f2h(acc[i][j][r] + bv);
            } else {
                short4_t o;
                #pragma unroll
                for (int r = 0; r < 4; ++r) o[r] = (short)f2h(acc[i][j][r] + bv);
                *(short4_t*)&Vt[(size_t)(col - COL_V) * MM + row] = o;
            }
        }
    }
}

// ---------------- flash attention (r11-exact): 8 waves x 16 q, permuted QK^T, K=32 PV --
__global__ __launch_bounds__(512, 4) void k_attn(
    const ushort_t* __restrict__ O, const ushort_t* __restrict__ Vt,
    float* __restrict__ Out) {

    __shared__ ushort_t sK[2][KVB * 128];     // [t][128], 4-bit mask swizzle, dbuf
    __shared__ ushort_t sVt[2][128 * KVB];    // [d][KVB], mask d&7, dbuf

    const int tid = threadIdx.x;
    const int w = tid >> 6, l = tid & 63;     // w in [0,8)
    const int lg = l >> 4, li = l & 15;
    const int q0 = blockIdx.x * 128;
    const int n = blockIdx.y, b = blockIdx.z;

    // Q fragments: rows q0 + w*16 + li
    h8 qv[4];
    {
        size_t base = ((size_t)(b * SS + q0 + w * 16 + li)) * NTOT + n * 128 + lg * 8;
        #pragma unroll
        for (int kk = 0; kk < 4; ++kk)
            qv[kk] = *(const h8*)&O[base + kk * 32];
    }

    f32x4 accO[8] = {};
    float m2 = -3.0e38f;
    float lsum = 0.f;

    auto stage = [&](int bi, int t0) {
        #pragma unroll
        for (int c = 0; c < 2; ++c) {
            int seg = c * 8 + w;                         // 16 segs over 8 waves
            int oe = seg * 512 + l * 8;
            int row = oe >> 7;
            int mk = (row & 3) | (((row >> 3) & 3) << 2);   // 4-bit: 16 distinct slots
            int ce = (oe & 127) ^ (mk << 3);
            size_t g = (size_t)(b * SS + t0 + row) * NTOT + COL_K + ce;
            load_lds16(O + g, &sK[bi][seg * 512]);
        }
        #pragma unroll
        for (int c = 0; c < 2; ++c) {
            int seg = c * 8 + w;
            int oe = seg * 512 + l * 8;
            int row = oe >> 6;
            int ce = (oe & 63) ^ ((row & 7) << 3);
            size_t g = (size_t)row * MM + b * SS + t0 + ce;
            load_lds16(Vt + g, &sVt[bi][seg * 512]);
        }
    };

    stage(0, 0);
    constexpr int NT = SS / KVB;   // 16

    for (int it = 0; it < NT; ++it) {
        const int cur = it & 1;
        const int t0 = it * KVB;
        __syncthreads();                       // drains stage(cur)
        if (it + 1 < NT) stage(cur ^ 1, t0 + KVB);
        const ushort_t* sKc = sK[cur];
        const ushort_t* sVc = sVt[cur];

        // ---- QK^T, permuted A-rows: reg r of s[ts] = S[t=(ts&1)*32+lg*8+(ts>>1)*4+r][q=li]
        f32x4 s[4] = {};
        __builtin_amdgcn_s_setprio(1);
        #pragma unroll
        for (int ts = 0; ts < 4; ++ts) {
            int trow = (ts & 1) * 32 + ((li >> 2) << 3) + ((ts >> 1) << 2) + (li & 3);
            int mk = (trow & 3) | (((trow >> 3) & 3) << 2);
            #pragma unroll
            for (int kk = 0; kk < 4; ++kk) {
                h8 kv = *(const h8*)&sKc[trow * 128 + ((kk * 32 + lg * 8) ^ (mk << 3))];
                s[ts] = mfma16h(kv, qv[kk], s[ts]);     // A=K, B=Q -> S^T
            }
        }
        __builtin_amdgcn_s_setprio(0);

        // ---- in-register online softmax (row q = li; 16 t-values per lane)
        float v = fmaxf(fmaxf(s[0][0], s[0][1]), fmaxf(s[0][2], s[0][3]));
        #pragma unroll
        for (int ts = 1; ts < 4; ++ts)
            v = fmaxf(v, fmaxf(fmaxf(s[ts][0], s[ts][1]), fmaxf(s[ts][2], s[ts][3])));
        v = fmaxf(v, __shfl_xor(v, 16));
        v = fmaxf(v, __shfl_xor(v, 32));
        float pm2 = v * L2E;

        if (!__all(pm2 <= m2 + 11.54f)) {   // defer-max, THR = 8 nats
            float mn = fmaxf(m2, pm2);
            float scl = exp2f(m2 - mn);
            lsum *= scl;
            #pragma unroll
            for (int db = 0; db < 8; ++db)
                #pragma unroll
                for (int r = 0; r < 4; ++r) accO[db][r] *= scl;
            m2 = mn;
        }

        h8 pb[2];
        #pragma unroll
        for (int ts = 0; ts < 4; ++ts)
            #pragma unroll
            for (int r = 0; r < 4; ++r) {
                float p = exp2f(fmaf(s[ts][r], L2E, -m2));
                lsum += p;
                pb[ts & 1][((ts >> 1) << 2) + r] = (half_t)p;
            }

        // ---- PV: K=32, b128 V^T reads from LDS
        __builtin_amdgcn_s_setprio(1);
        #pragma unroll
        for (int db = 0; db < 8; ++db) {
            int d = db * 16 + li;
            const ushort_t* vbase = &sVc[d * KVB];
            int sw = (d & 7) << 3;
            #pragma unroll
            for (int ks = 0; ks < 2; ++ks) {
                h8 va = *(const h8*)&vbase[(ks * 32 + lg * 8) ^ sw];
                accO[db] = mfma16h(va, pb[ks], accO[db]);
            }
        }
        __builtin_amdgcn_s_setprio(0);
    }

    // ---- epilogue: finish denominator, normalize, write f32 [B][N][S][D]
    lsum += __shfl_xor(lsum, 16);
    lsum += __shfl_xor(lsum, 32);
    float inv = 1.0f / lsum;
    int q = q0 + w * 16 + li;
    size_t base = (((size_t)b * NH + n) * SS + q) * DD;
    #pragma unroll
    for (int db = 0; db < 8; ++db) {
        f4 o;
        #pragma unroll
        for (int r = 0; r < 4; ++r) o[r] = accO[db][r] * inv;
        *(f4*)&Out[base + db * 16 + lg * 4] = o;
    }
}

// ---------------- workspace layout (bytes) ----------------
#define OFF_HC    ((size_t)0)                          // hidden fp16 [MM][HH]
#define OFF_BC    (OFF_HC + (size_t)MM*HH*2)           // Bcat fp16 [NTOT][HH]
#define OFF_O     (OFF_BC + (size_t)NTOT*HH*2)         // O fp16 [MM][NTOT]
#define OFF_VT    (OFF_O + (size_t)MM*NTOT*2)          // Vt fp16 [128][MM]

extern "C" void kernel_launch(void* const* d_in, const int* in_sizes, int n_in,
                              void* d_out, int out_size, void* d_ws, size_t ws_size,
                              hipStream_t stream) {
    const float* hs = (const float*)d_in[0];
    const float* Wq = (const float*)d_in[1];
    const float* bq = (const float*)d_in[2];
    const float* Wk = (const float*)d_in[3];
    const float* bk = (const float*)d_in[4];
    const float* Wv = (const float*)d_in[5];
    const float* bv = (const float*)d_in[6];
    float* out = (float*)d_out;
    char* ws = (char*)d_ws;

    ushort_t* hc   = (ushort_t*)(ws + OFF_HC);
    ushort_t* bcat = (ushort_t*)(ws + OFF_BC);
    ushort_t* Obuf = (ushort_t*)(ws + OFF_O);
    ushort_t* vt   = (ushort_t*)(ws + OFF_VT);

    // prep
    k_cvt<<<(MM*HH)/(256*8), 256, 0, stream>>>(hs, hc, MM*HH);
    dim3 gwq(HH/64, DD/64, NH);
    k_tw<<<gwq, 256, 0, stream>>>(Wq, bcat, DD);
    dim3 gwk(HH/64, DD/64, 1);
    k_tw<<<gwk, 256, 0, stream>>>(Wk, bcat + (size_t)COL_K*HH, DD);
    k_tw<<<gwk, 256, 0, stream>>>(Wv, bcat + (size_t)COL_V*HH, DD);

    // merged projection GEMM: 4096 x 2304 x 2048, bias fused, V^T written directly
    k_gemm<<<(MM/128)*(NTOT/128), 256, 0, stream>>>(hc, bcat, bq, bk, bv, Obuf, vt);

    // attention (r11-exact)
    dim3 ga(SS/128, NH, NB);
    k_attn<<<ga, 512, 0, stream>>>(Obuf, vt, out);
}

// Round 18
// 120.440 us; speedup vs baseline: 1.1370x; 1.0370x over previous
//
#include <hip/hip_runtime.h>
#include <hip/hip_bf16.h>

typedef unsigned short ushort_t;
typedef _Float16 half_t;
typedef __attribute__((ext_vector_type(8))) _Float16 h8;     // 8 fp16 (K=32 MFMA A/B frag)
typedef __attribute__((ext_vector_type(8))) short short8;
typedef __attribute__((ext_vector_type(4))) short short4_t;  // 8B store
typedef __attribute__((ext_vector_type(4))) float f32x4;
typedef __attribute__((ext_vector_type(4))) float f4;

#define NB 4
#define SS 1024
#define HH 2048
#define NH 16
#define DD 128
#define MM (NB*SS)          // 4096 rows
#define NTOT 2304           // 2048 Q cols | 128 K | 128 V
#define COL_K 2048
#define COL_V 2176
#define KVB 64
#define L2E 1.44269504089f

__device__ __forceinline__ ushort_t f2h(float x) {
    half_t h = (half_t)x;
    return *(ushort_t*)&h;
}
__device__ __forceinline__ f32x4 mfma16h(h8 a, h8 b, f32x4 c) {
    return __builtin_amdgcn_mfma_f32_16x16x32_f16(a, b, c, 0, 0, 0);
}
__device__ __forceinline__ void load_lds16(const ushort_t* g, ushort_t* l) {
    __builtin_amdgcn_global_load_lds(
        (const __attribute__((address_space(1))) unsigned int*)g,
        (__attribute__((address_space(3))) unsigned int*)l,
        16, 0, 0);
}

// ---------------- f32 -> fp16 convert (hidden states) ----------------
__global__ void k_cvt(const float* __restrict__ src, ushort_t* __restrict__ dst, int n) {
    int i = (blockIdx.x * blockDim.x + threadIdx.x) * 8;
    if (i + 7 < n) {
        f4 a = *(const f4*)(src + i);
        f4 b = *(const f4*)(src + i + 4);
        short8 o;
        #pragma unroll
        for (int j = 0; j < 4; ++j) { o[j] = (short)f2h(a[j]); o[4 + j] = (short)f2h(b[j]); }
        *(short8*)(dst + i) = o;
    }
}

// ---------------- fused weight transpose+convert: {Wq heads 0-15, Wk, Wv} -> Bcat ------
// z in [0,18): z<16 -> Wq head z (rows z*DD..), z==16 -> Wk (rows COL_K..), z==17 -> Wv
// (rows COL_V..). All sources are [HH][DD] f32; dest rows of Bcat [NTOT][HH] fp16.
// One dispatch replaces the former three (launch-bubble removal; bodies identical).
__global__ __launch_bounds__(256) void k_tw_all(const float* __restrict__ Wq,
                                                const float* __restrict__ Wk,
                                                const float* __restrict__ Wv,
                                                ushort_t* __restrict__ T) {
    __shared__ ushort_t t[64][74];
    const int z = blockIdx.z;
    const float* W = (z < 16) ? (Wq + (size_t)z * HH * DD) : ((z == 16) ? Wk : Wv);
    const int rowBase = (z < 16) ? z * DD : ((z == 16) ? COL_K : COL_V);
    const int h0 = blockIdx.x * 64, d0 = blockIdx.y * 64;
    const int r = threadIdx.x >> 2, cg = (threadIdx.x & 3) * 16;
    const float* src = W + ((size_t)(h0 + r)) * DD + d0 + cg;
    #pragma unroll
    for (int v = 0; v < 4; ++v) {
        f4 a = *(const f4*)(src + v * 4);
        #pragma unroll
        for (int j = 0; j < 4; ++j) t[r][cg + v * 4 + j] = f2h(a[j]);
    }
    __syncthreads();
    short8 o0, o1;
    #pragma unroll
    for (int j = 0; j < 8; ++j) { o0[j] = (short)t[cg + j][r]; o1[j] = (short)t[cg + 8 + j][r]; }
    ushort_t* dst = T + ((size_t)(rowBase + d0 + r)) * HH + h0 + cg;
    *(short8*)dst = o0;
    *(short8*)(dst + 8) = o1;
}

// ---------------- fp16 GEMM (r17: r11 structure + both-sides LDS swizzle) --------------
// O[M][NTOT] = A[M][HH] * B[NTOT][HH]^T + bias (fused); V cols written transposed to Vt.
// 4 waves, 128x128 tile, BK=32, single-buffer LDS, lockstep __syncthreads (pipeline /
// 3-buf / 8-wave variants all measured worse: r12/r13/r16). 16B-chunk XOR swizzle
// chunk ^= (row>>1)&3 on BOTH staging source and fragment reads (conflicts -> 0, r17).
__global__ __launch_bounds__(256) void k_gemm(
    const ushort_t* __restrict__ A, const ushort_t* __restrict__ B,
    const float* __restrict__ bq, const float* __restrict__ bk,
    const float* __restrict__ bvv, ushort_t* __restrict__ O,
    ushort_t* __restrict__ Vt) {

    constexpr int BK = 32;
    __shared__ ushort_t sA[128 * BK], sB[128 * BK];

    const int bid = blockIdx.x;
    const int swz = (bid & 7) * 72 + (bid >> 3);     // 576/8 = 72 per XCD, bijective
    const int m0 = (swz & 31) * 128;
    const int n0 = (swz >> 5) * 128;

    const int tid = threadIdx.x;
    const int w = tid >> 6, l = tid & 63;
    const int wr = w >> 1, wc = w & 1;
    f32x4 acc[4][4] = {};

    for (int kt = 0; kt < HH / BK; ++kt) {
        const int k0 = kt * BK;
        #pragma unroll
        for (int c = 0; c < 2; ++c) {
            int chunk = c * 4 + w;
            int idx = chunk * 512 + l * 8;
            int row = idx >> 5;
            int kc = (idx & 31) ^ (((row >> 1) & 3) << 3);   // pre-swizzled source
            load_lds16(A + (size_t)(m0 + row) * HH + k0 + kc, &sA[chunk * 512]);
            load_lds16(B + (size_t)(n0 + row) * HH + k0 + kc, &sB[chunk * 512]);
        }
        __syncthreads();

        h8 a[4], b[4];
        #pragma unroll
        for (int i = 0; i < 4; ++i) {
            int ra = wr * 64 + i * 16 + (l & 15);
            int rb = wc * 64 + i * 16 + (l & 15);
            a[i] = *(const h8*)&sA[ra * 32 + (((l >> 4) ^ ((ra >> 1) & 3)) << 3)];
            b[i] = *(const h8*)&sB[rb * 32 + (((l >> 4) ^ ((rb >> 1) & 3)) << 3)];
        }
        #pragma unroll
        for (int i = 0; i < 4; ++i)
            #pragma unroll
            for (int j = 0; j < 4; ++j)
                acc[i][j] = mfma16h(a[i], b[j], acc[i][j]);
        __syncthreads();
    }

    #pragma unroll
    for (int i = 0; i < 4; ++i) {
        int row = m0 + wr * 64 + i * 16 + ((l >> 4) << 2);
        #pragma unroll
        for (int j = 0; j < 4; ++j) {
            int col = n0 + wc * 64 + j * 16 + (l & 15);
            float bv = (col < COL_K) ? bq[col]
                     : (col < COL_V) ? bk[col - COL_K]
                                     : bvv[col - COL_V];
            if (col < COL_V) {
                #pragma unroll
                for (int r = 0; r < 4; ++r)
                    O[(size_t)(row + r) * NTOT + col] = f2h(acc[i][j][r] + bv);
            } else {
                short4_t o;
                #pragma unroll
                for (int r = 0; r < 4; ++r) o[r] = (short)f2h(acc[i][j][r] + bv);
                *(short4_t*)&Vt[(size_t)(col - COL_V) * MM + row] = o;
            }
        }
    }
}

// ---------------- flash attention (r11-exact): 8 waves x 16 q, permuted QK^T, K=32 PV --
__global__ __launch_bounds__(512, 4) void k_attn(
    const ushort_t* __restrict__ O, const ushort_t* __restrict__ Vt,
    float* __restrict__ Out) {

    __shared__ ushort_t sK[2][KVB * 128];     // [t][128], 4-bit mask swizzle, dbuf
    __shared__ ushort_t sVt[2][128 * KVB];    // [d][KVB], mask d&7, dbuf

    const int tid = threadIdx.x;
    const int w = tid >> 6, l = tid & 63;     // w in [0,8)
    const int lg = l >> 4, li = l & 15;
    const int q0 = blockIdx.x * 128;
    const int n = blockIdx.y, b = blockIdx.z;

    // Q fragments: rows q0 + w*16 + li
    h8 qv[4];
    {
        size_t base = ((size_t)(b * SS + q0 + w * 16 + li)) * NTOT + n * 128 + lg * 8;
        #pragma unroll
        for (int kk = 0; kk < 4; ++kk)
            qv[kk] = *(const h8*)&O[base + kk * 32];
    }

    f32x4 accO[8] = {};
    float m2 = -3.0e38f;
    float lsum = 0.f;

    auto stage = [&](int bi, int t0) {
        #pragma unroll
        for (int c = 0; c < 2; ++c) {
            int seg = c * 8 + w;                         // 16 segs over 8 waves
            int oe = seg * 512 + l * 8;
            int row = oe >> 7;
            int mk = (row & 3) | (((row >> 3) & 3) << 2);   // 4-bit: 16 distinct slots
            int ce = (oe & 127) ^ (mk << 3);
            size_t g = (size_t)(b * SS + t0 + row) * NTOT + COL_K + ce;
            load_lds16(O + g, &sK[bi][seg * 512]);
        }
        #pragma unroll
        for (int c = 0; c < 2; ++c) {
            int seg = c * 8 + w;
            int oe = seg * 512 + l * 8;
            int row = oe >> 6;
            int ce = (oe & 63) ^ ((row & 7) << 3);
            size_t g = (size_t)row * MM + b * SS + t0 + ce;
            load_lds16(Vt + g, &sVt[bi][seg * 512]);
        }
    };

    stage(0, 0);
    constexpr int NT = SS / KVB;   // 16

    for (int it = 0; it < NT; ++it) {
        const int cur = it & 1;
        const int t0 = it * KVB;
        __syncthreads();                       // drains stage(cur)
        if (it + 1 < NT) stage(cur ^ 1, t0 + KVB);
        const ushort_t* sKc = sK[cur];
        const ushort_t* sVc = sVt[cur];

        // ---- QK^T, permuted A-rows: reg r of s[ts] = S[t=(ts&1)*32+lg*8+(ts>>1)*4+r][q=li]
        f32x4 s[4] = {};
        __builtin_amdgcn_s_setprio(1);
        #pragma unroll
        for (int ts = 0; ts < 4; ++ts) {
            int trow = (ts & 1) * 32 + ((li >> 2) << 3) + ((ts >> 1) << 2) + (li & 3);
            int mk = (trow & 3) | (((trow >> 3) & 3) << 2);
            #pragma unroll
            for (int kk = 0; kk < 4; ++kk) {
                h8 kv = *(const h8*)&sKc[trow * 128 + ((kk * 32 + lg * 8) ^ (mk << 3))];
                s[ts] = mfma16h(kv, qv[kk], s[ts]);     // A=K, B=Q -> S^T
            }
        }
        __builtin_amdgcn_s_setprio(0);

        // ---- in-register online softmax (row q = li; 16 t-values per lane)
        float v = fmaxf(fmaxf(s[0][0], s[0][1]), fmaxf(s[0][2], s[0][3]));
        #pragma unroll
        for (int ts = 1; ts < 4; ++ts)
            v = fmaxf(v, fmaxf(fmaxf(s[ts][0], s[ts][1]), fmaxf(s[ts][2], s[ts][3])));
        v = fmaxf(v, __shfl_xor(v, 16));
        v = fmaxf(v, __shfl_xor(v, 32));
        float pm2 = v * L2E;

        if (!__all(pm2 <= m2 + 11.54f)) {   // defer-max, THR = 8 nats
            float mn = fmaxf(m2, pm2);
            float scl = exp2f(m2 - mn);
            lsum *= scl;
            #pragma unroll
            for (int db = 0; db < 8; ++db)
                #pragma unroll
                for (int r = 0; r < 4; ++r) accO[db][r] *= scl;
            m2 = mn;
        }

        h8 pb[2];
        #pragma unroll
        for (int ts = 0; ts < 4; ++ts)
            #pragma unroll
            for (int r = 0; r < 4; ++r) {
                float p = exp2f(fmaf(s[ts][r], L2E, -m2));
                lsum += p;
                pb[ts & 1][((ts >> 1) << 2) + r] = (half_t)p;
            }

        // ---- PV: K=32, b128 V^T reads from LDS
        __builtin_amdgcn_s_setprio(1);
        #pragma unroll
        for (int db = 0; db < 8; ++db) {
            int d = db * 16 + li;
            const ushort_t* vbase = &sVc[d * KVB];
            int sw = (d & 7) << 3;
            #pragma unroll
            for (int ks = 0; ks < 2; ++ks) {
                h8 va = *(const h8*)&vbase[(ks * 32 + lg * 8) ^ sw];
                accO[db] = mfma16h(va, pb[ks], accO[db]);
            }
        }
        __builtin_amdgcn_s_setprio(0);
    }

    // ---- epilogue: finish denominator, normalize, write f32 [B][N][S][D]
    lsum += __shfl_xor(lsum, 16);
    lsum += __shfl_xor(lsum, 32);
    float inv = 1.0f / lsum;
    int q = q0 + w * 16 + li;
    size_t base = (((size_t)b * NH + n) * SS + q) * DD;
    #pragma unroll
    for (int db = 0; db < 8; ++db) {
        f4 o;
        #pragma unroll
        for (int r = 0; r < 4; ++r) o[r] = accO[db][r] * inv;
        *(f4*)&Out[base + db * 16 + lg * 4] = o;
    }
}

// ---------------- workspace layout (bytes) ----------------
#define OFF_HC    ((size_t)0)                          // hidden fp16 [MM][HH]
#define OFF_BC    (OFF_HC + (size_t)MM*HH*2)           // Bcat fp16 [NTOT][HH]
#define OFF_O     (OFF_BC + (size_t)NTOT*HH*2)         // O fp16 [MM][NTOT]
#define OFF_VT    (OFF_O + (size_t)MM*NTOT*2)          // Vt fp16 [128][MM]

extern "C" void kernel_launch(void* const* d_in, const int* in_sizes, int n_in,
                              void* d_out, int out_size, void* d_ws, size_t ws_size,
                              hipStream_t stream) {
    const float* hs = (const float*)d_in[0];
    const float* Wq = (const float*)d_in[1];
    const float* bq = (const float*)d_in[2];
    const float* Wk = (const float*)d_in[3];
    const float* bk = (const float*)d_in[4];
    const float* Wv = (const float*)d_in[5];
    const float* bv = (const float*)d_in[6];
    float* out = (float*)d_out;
    char* ws = (char*)d_ws;

    ushort_t* hc   = (ushort_t*)(ws + OFF_HC);
    ushort_t* bcat = (ushort_t*)(ws + OFF_BC);
    ushort_t* Obuf = (ushort_t*)(ws + OFF_O);
    ushort_t* vt   = (ushort_t*)(ws + OFF_VT);

    // prep: 2 dispatches (was 4)
    k_cvt<<<(MM*HH)/(256*8), 256, 0, stream>>>(hs, hc, MM*HH);
    dim3 gtw(HH/64, DD/64, 18);
    k_tw_all<<<gtw, 256, 0, stream>>>(Wq, Wk, Wv, bcat);

    // merged projection GEMM: 4096 x 2304 x 2048, bias fused, V^T written directly
    k_gemm<<<(MM/128)*(NTOT/128), 256, 0, stream>>>(hc, bcat, bq, bk, bv, Obuf, vt);

    // attention (r11-exact)
    dim3 ga(SS/128, NH, NB);
    k_attn<<<ga, 512, 0, stream>>>(Obuf, vt, out);
}